// Round 1
// baseline (12481.120 us; speedup 1.0000x reference)
//
#include <hip/hip_runtime.h>

// LSTM_27152783245909 — persistent-recurrence LSTM for MI355X (gfx950)
// Pipeline: cvt_w (W_out->bf16) ; transpose_x (x[B,I,T] -> xT[T,B,I] bf16) ;
//           lstm_rec (256 persistent blocks, VGPR-resident weights, atomic grid
//           barrier per timestep, dumps c_t bf16) ;
//           lstm_head (parallel [T*B,512] GEMM + fused row softmax).

#define T_ 256
#define NBLK 256u

typedef __attribute__((ext_vector_type(8))) short bf16x8;
typedef __attribute__((ext_vector_type(4))) float floatx4;

__device__ __forceinline__ unsigned short f2bf(float f) {
  unsigned u = __builtin_bit_cast(unsigned, f);
  u += 0x7FFFu + ((u >> 16) & 1u);   // round-nearest-even
  return (unsigned short)(u >> 16);
}

__device__ __forceinline__ float sigm(float x) { return 1.0f / (1.0f + __expf(-x)); }

// Grid barrier: monotonic counter, release on arrive, relaxed spin (avoids
// repeated L2 invalidation while polling), acquire fence on exit.
__device__ __forceinline__ void gbar(unsigned* cnt, unsigned target) {
  __syncthreads();                        // all waves' stores reach L2 (vmcnt drain)
  if (threadIdx.x == 0) {
    __threadfence();                      // agent release: writeback XCD L2
    __hip_atomic_fetch_add(cnt, 1u, __ATOMIC_RELEASE, __HIP_MEMORY_SCOPE_AGENT);
    while (__hip_atomic_load(cnt, __ATOMIC_RELAXED, __HIP_MEMORY_SCOPE_AGENT) < target)
      __builtin_amdgcn_s_sleep(1);
  }
  __syncthreads();
  __threadfence();                        // agent acquire: invalidate stale caches
}

// ---------------- W_out fp32 -> bf16 (512x1024) ----------------
__global__ void cvt_w(const float* __restrict__ w, unsigned short* __restrict__ o) {
  const size_t g = (size_t)blockIdx.x * 256 + threadIdx.x;  // 65536 threads * 8 elems
  const float* s = w + g * 8;
  bf16x8 v;
#pragma unroll
  for (int i = 0; i < 8; ++i) v[i] = (short)f2bf(s[i]);
  *(bf16x8*)(o + g * 8) = v;
}

// ---------------- x[B=64, I=512, T=256] fp32 -> xT[T,B,I] bf16 ----------------
__global__ void transpose_x(const float* __restrict__ x, unsigned short* __restrict__ xT) {
  __shared__ float tile[32][33];
  const int b = blockIdx.z, i0 = blockIdx.y * 32, t0 = blockIdx.x * 32;
  const int tx = threadIdx.x & 31, ty = threadIdx.x >> 5;  // 32 x 8
#pragma unroll
  for (int p = 0; p < 4; ++p) {
    const int i = ty + p * 8;
    tile[i][tx] = x[((size_t)b * 512 + i0 + i) * 256 + t0 + tx];
  }
  __syncthreads();
#pragma unroll
  for (int p = 0; p < 4; ++p) {
    const int t = ty + p * 8;
    xT[((size_t)(t0 + t) * 64 + b) * 512 + i0 + tx] = f2bf(tile[tx][t]);
  }
}

// ---------------- persistent recurrence ----------------
// 256 blocks x 512 thr. Block (mg,ng): batch rows [16mg,16mg+16), hidden units
// [16ng,16ng+16) i.e. gate cols {g*1024 + 16ng + j}. Wave (nh = gate pair,
// kq = K quarter of 1536). Weights live in VGPRs (bfrag), c in thread registers.
__global__ __launch_bounds__(512, 2) void lstm_rec(
    const float* __restrict__ Whh, const float* __restrict__ Wih,
    const float* __restrict__ bih, const float* __restrict__ bhh,
    const float* __restrict__ h0, const float* __restrict__ c0,
    const unsigned short* __restrict__ xT,
    unsigned short* __restrict__ hbuf,   // [2][64][1024] bf16
    unsigned short* __restrict__ call,   // [256][64][1024] bf16
    unsigned* __restrict__ cnt)
{
  const int tid = threadIdx.x;
  const int lane = tid & 63;
  const int wv = tid >> 6;           // 0..7
  const int nh = wv & 1, kq = wv >> 1;
  const int mg = blockIdx.x & 3, ng = blockIdx.x >> 2;
  const int l15 = lane & 15, lq = lane >> 4;
  const int row = mg * 16 + l15;     // A-fragment batch row

  __shared__ float gpart[4][16][66]; // [kq][m][gate*16+j], pad 66 vs bank conflicts

  // persistent B fragments: 2 gates x 12 ksteps = 96 VGPRs/lane
  bf16x8 bfrag[2][12];
#pragma unroll
  for (int nt = 0; nt < 2; ++nt) {
    const int ncol = (2 * nh + nt) * 1024 + ng * 16 + l15;
#pragma unroll
    for (int ks = 0; ks < 12; ++ks) {
      const int kg = kq * 384 + ks * 32 + lq * 8;   // never straddles 1024
      const float* s = (kg < 1024) ? (Whh + (size_t)ncol * 1024 + kg)
                                   : (Wih + (size_t)ncol * 512 + (kg - 1024));
      bf16x8 v;
#pragma unroll
      for (int i = 0; i < 8; ++i) v[i] = (short)f2bf(s[i]);
      bfrag[nt][ks] = v;
    }
  }

  // per-thread state (waves 0..3): one (batch m, unit j) cell each
  const int m_loc = tid >> 4, j = tid & 15;
  const int row_g = mg * 16 + m_loc;
  const int unit = ng * 16 + j;
  float c_reg = 0.f, bs0 = 0.f, bs1 = 0.f, bs2 = 0.f, bs3 = 0.f;
  if (tid < 256) {
    c_reg = c0[unit];
    bs0 = bih[unit] + bhh[unit];
    bs1 = bih[1024 + unit] + bhh[1024 + unit];
    bs2 = bih[2048 + unit] + bhh[2048 + unit];
    bs3 = bih[3072 + unit] + bhh[3072 + unit];
    hbuf[65536 + row_g * 1024 + unit] = f2bf(h0[unit]);  // h_{-1} into slot 1
  }
  gbar(cnt, NBLK);

  for (int t = 0; t < T_; ++t) {
    const unsigned short* hprev = hbuf + ((t + 1) & 1) * 65536;
    const unsigned short* bh = hprev + (size_t)row * 1024;
    const unsigned short* bx = xT + ((size_t)t * 64 + row) * 512;
    floatx4 zero = {0.f, 0.f, 0.f, 0.f};
    floatx4 acc0 = zero, acc1 = zero;
#pragma unroll
    for (int ks = 0; ks < 12; ++ks) {
      const int kg = kq * 384 + ks * 32 + lq * 8;
      const unsigned short* ap = (kg < 1024) ? (bh + kg) : (bx + (kg - 1024));
      const bf16x8 af = *(const bf16x8*)ap;
      acc0 = __builtin_amdgcn_mfma_f32_16x16x32_bf16(af, bfrag[0][ks], acc0, 0, 0, 0);
      acc1 = __builtin_amdgcn_mfma_f32_16x16x32_bf16(af, bfrag[1][ks], acc1, 0, 0, 0);
    }
    // C layout: col = lane&15, row = (lane>>4)*4 + r
#pragma unroll
    for (int r = 0; r < 4; ++r) {
      gpart[kq][lq * 4 + r][(2 * nh) * 16 + l15]     = acc0[r];
      gpart[kq][lq * 4 + r][(2 * nh + 1) * 16 + l15] = acc1[r];
    }
    __syncthreads();
    if (tid < 256) {
      float gi = bs0, gf = bs1, gg = bs2, go = bs3;
#pragma unroll
      for (int q = 0; q < 4; ++q) {
        gi += gpart[q][m_loc][j];
        gf += gpart[q][m_loc][16 + j];
        gg += gpart[q][m_loc][32 + j];
        go += gpart[q][m_loc][48 + j];
      }
      const float iv = sigm(gi), fv = sigm(gf), gv = tanhf(gg), ov = sigm(go);
      c_reg = fv * c_reg + iv * gv;
      const float hv = ov * tanhf(c_reg);
      hbuf[(t & 1) * 65536 + row_g * 1024 + unit] = f2bf(hv);
      call[((size_t)t * 64 + row_g) * 1024 + unit] = f2bf(c_reg);
    }
    gbar(cnt, (unsigned)(t + 2) * NBLK);
  }
}

// ---------------- output head: logits + softmax, fully parallel over t ----------------
// One block per t: [64 x 512] = c_t[64,1024] @ W_out^T. Wave wv owns oc in
// [128wv,128wv+128) (8 n-tiles) x all 64 rows (4 m-tiles). Cross-wave softmax via LDS.
__global__ __launch_bounds__(256, 1) void lstm_head(
    const unsigned short* __restrict__ call,
    const unsigned short* __restrict__ wout,
    const float* __restrict__ bout,
    float* __restrict__ out)
{
  const int tb = blockIdx.x;
  const int lane = threadIdx.x & 63;
  const int wv = threadIdx.x >> 6;
  const int l15 = lane & 15, lq = lane >> 4;

  __shared__ float sred[2][4][64];

  floatx4 zero = {0.f, 0.f, 0.f, 0.f};
  floatx4 acc[4][8];
#pragma unroll
  for (int mt = 0; mt < 4; ++mt)
#pragma unroll
    for (int nt = 0; nt < 8; ++nt) acc[mt][nt] = zero;

  const unsigned short* abase = call + ((size_t)tb * 64 + l15) * 1024 + lq * 8;
  const unsigned short* bbase = wout + ((size_t)(wv * 128 + l15)) * 1024 + lq * 8;

#pragma unroll 2
  for (int ks = 0; ks < 32; ++ks) {
    bf16x8 a[4];
#pragma unroll
    for (int mt = 0; mt < 4; ++mt)
      a[mt] = *(const bf16x8*)(abase + (size_t)mt * 16 * 1024 + ks * 32);
#pragma unroll
    for (int nt = 0; nt < 8; ++nt) {
      const bf16x8 b = *(const bf16x8*)(bbase + (size_t)nt * 16 * 1024 + ks * 32);
#pragma unroll
      for (int mt = 0; mt < 4; ++mt)
        acc[mt][nt] = __builtin_amdgcn_mfma_f32_16x16x32_bf16(a[mt], b, acc[mt][nt], 0, 0, 0);
    }
  }

#pragma unroll
  for (int nt = 0; nt < 8; ++nt) {
    const float bo = bout[wv * 128 + nt * 16 + l15];
#pragma unroll
    for (int mt = 0; mt < 4; ++mt)
#pragma unroll
      for (int r = 0; r < 4; ++r) acc[mt][nt][r] += bo;
  }

  // row max: rows = mt*16 + lq*4 + r, owned by the 16 lanes sharing lq
  float rmax[4][4];
#pragma unroll
  for (int mt = 0; mt < 4; ++mt)
#pragma unroll
    for (int r = 0; r < 4; ++r) {
      float m = acc[mt][0][r];
#pragma unroll
      for (int nt = 1; nt < 8; ++nt) m = fmaxf(m, acc[mt][nt][r]);
      m = fmaxf(m, __shfl_xor(m, 1, 64));
      m = fmaxf(m, __shfl_xor(m, 2, 64));
      m = fmaxf(m, __shfl_xor(m, 4, 64));
      m = fmaxf(m, __shfl_xor(m, 8, 64));
      rmax[mt][r] = m;
    }
  if (l15 == 0) {
#pragma unroll
    for (int mt = 0; mt < 4; ++mt)
#pragma unroll
      for (int r = 0; r < 4; ++r) sred[0][wv][mt * 16 + lq * 4 + r] = rmax[mt][r];
  }
  __syncthreads();
  float gmax[4][4], rsum[4][4];
#pragma unroll
  for (int mt = 0; mt < 4; ++mt)
#pragma unroll
    for (int r = 0; r < 4; ++r) {
      const int rw = mt * 16 + lq * 4 + r;
      gmax[mt][r] = fmaxf(fmaxf(sred[0][0][rw], sred[0][1][rw]),
                          fmaxf(sred[0][2][rw], sred[0][3][rw]));
      rsum[mt][r] = 0.f;
    }
#pragma unroll
  for (int mt = 0; mt < 4; ++mt)
#pragma unroll
    for (int nt = 0; nt < 8; ++nt)
#pragma unroll
      for (int r = 0; r < 4; ++r) {
        const float e = __expf(acc[mt][nt][r] - gmax[mt][r]);
        acc[mt][nt][r] = e;
        rsum[mt][r] += e;
      }
#pragma unroll
  for (int mt = 0; mt < 4; ++mt)
#pragma unroll
    for (int r = 0; r < 4; ++r) {
      float s = rsum[mt][r];
      s += __shfl_xor(s, 1, 64);
      s += __shfl_xor(s, 2, 64);
      s += __shfl_xor(s, 4, 64);
      s += __shfl_xor(s, 8, 64);
      rsum[mt][r] = s;
    }
  if (l15 == 0) {
#pragma unroll
    for (int mt = 0; mt < 4; ++mt)
#pragma unroll
      for (int r = 0; r < 4; ++r) sred[1][wv][mt * 16 + lq * 4 + r] = rsum[mt][r];
  }
  __syncthreads();
#pragma unroll
  for (int mt = 0; mt < 4; ++mt)
#pragma unroll
    for (int r = 0; r < 4; ++r) {
      const int rw = mt * 16 + lq * 4 + r;
      const float inv = 1.0f / (sred[1][0][rw] + sred[1][1][rw] +
                                sred[1][2][rw] + sred[1][3][rw]);
      float* orow = out + ((size_t)tb * 64 + rw) * 512 + wv * 128 + l15;
#pragma unroll
      for (int nt = 0; nt < 8; ++nt) orow[nt * 16] = acc[mt][nt][r] * inv;
    }
}

// ---------------- launch ----------------
extern "C" void kernel_launch(void* const* d_in, const int* in_sizes, int n_in,
                              void* d_out, int out_size, void* d_ws, size_t ws_size,
                              hipStream_t stream) {
  const float* x    = (const float*)d_in[0];
  const float* Wih  = (const float*)d_in[1];
  const float* Whh  = (const float*)d_in[2];
  const float* bih  = (const float*)d_in[3];
  const float* bhh  = (const float*)d_in[4];
  const float* Wout = (const float*)d_in[5];
  const float* bout = (const float*)d_in[6];
  const float* h0   = (const float*)d_in[7];
  const float* c0   = (const float*)d_in[8];
  float* out = (float*)d_out;

  char* ws = (char*)d_ws;
  unsigned* cnt         = (unsigned*)(ws + 0);                  //   256 B
  unsigned short* hbuf  = (unsigned short*)(ws + 256);          //   256 KB
  unsigned short* woutb = (unsigned short*)(ws + 262400);       //     1 MB
  unsigned short* xT    = (unsigned short*)(ws + 1310976);      //    16 MB
  unsigned short* call  = (unsigned short*)(ws + 18088192);     //    32 MB

  hipMemsetAsync(cnt, 0, 256, stream);
  cvt_w<<<256, 256, 0, stream>>>(Wout, woutb);
  transpose_x<<<dim3(8, 16, 64), 256, 0, stream>>>(x, xT);
  lstm_rec<<<NBLK, 512, 0, stream>>>(Whh, Wih, bih, bhh, h0, c0, xT, hbuf, call, cnt);
  lstm_head<<<256, 256, 0, stream>>>(call, woutb, bout, out);
}

// Round 2
// 2842.063 us; speedup vs baseline: 4.3916x; 4.3916x over previous
//
#include <hip/hip_runtime.h>

// LSTM_27152783245909 — persistent-recurrence LSTM for MI355X (gfx950)
// R2: replaced single-atomic-counter grid barrier (256 serialized cross-XCD
// same-line RMWs/step ≈ 46 us/step, measured R1) with per-block flag lines +
// lane-parallel all-to-all polling, split into 4 independent per-mg groups.
// Pipeline: cvt_w ; transpose_x ; lstm_rec (256 persistent blocks, VGPR-resident
// weights, flag barrier per step, dumps c_t bf16) ; lstm_head (GEMM+softmax).

#define T_ 256

typedef __attribute__((ext_vector_type(8))) short bf16x8;
typedef __attribute__((ext_vector_type(4))) float floatx4;

__device__ __forceinline__ unsigned short f2bf(float f) {
  unsigned u = __builtin_bit_cast(unsigned, f);
  u += 0x7FFFu + ((u >> 16) & 1u);   // round-nearest-even
  return (unsigned short)(u >> 16);
}

__device__ __forceinline__ float sigm(float x) { return 1.0f / (1.0f + __expf(-x)); }

// ---------------- W_out fp32 -> bf16 (512x1024) ----------------
__global__ void cvt_w(const float* __restrict__ w, unsigned short* __restrict__ o) {
  const size_t g = (size_t)blockIdx.x * 256 + threadIdx.x;
  const float* s = w + g * 8;
  bf16x8 v;
#pragma unroll
  for (int i = 0; i < 8; ++i) v[i] = (short)f2bf(s[i]);
  *(bf16x8*)(o + g * 8) = v;
}

// ---------------- x[B=64, I=512, T=256] fp32 -> xT[T,B,I] bf16 ----------------
__global__ void transpose_x(const float* __restrict__ x, unsigned short* __restrict__ xT) {
  __shared__ float tile[32][33];
  const int b = blockIdx.z, i0 = blockIdx.y * 32, t0 = blockIdx.x * 32;
  const int tx = threadIdx.x & 31, ty = threadIdx.x >> 5;
#pragma unroll
  for (int p = 0; p < 4; ++p) {
    const int i = ty + p * 8;
    tile[i][tx] = x[((size_t)b * 512 + i0 + i) * 256 + t0 + tx];
  }
  __syncthreads();
#pragma unroll
  for (int p = 0; p < 4; ++p) {
    const int t = ty + p * 8;
    xT[((size_t)(t0 + t) * 64 + b) * 512 + i0 + tx] = f2bf(tile[tx][t]);
  }
}

// ---------------- persistent recurrence ----------------
// 256 blocks x 512 thr. Block (mg,ng): batch rows [16mg,16mg+16), hidden units
// [16ng,16ng+16). Wave (nh = gate pair, kq = K quarter of 1536). Weights live
// in VGPRs (96/lane), c in thread registers. Barrier: per-mg group of 64
// blocks; arrival = store-release own 64B flag line; detection = wave0 lane i
// polls member i's flag, __all(>= target); one acquire fence on exit.
__global__ __launch_bounds__(512, 2) void lstm_rec(
    const float* __restrict__ Whh, const float* __restrict__ Wih,
    const float* __restrict__ bih, const float* __restrict__ bhh,
    const float* __restrict__ h0, const float* __restrict__ c0,
    const unsigned short* __restrict__ xT,
    unsigned short* __restrict__ hbuf,   // [2][64][1024] bf16
    unsigned short* __restrict__ call,   // [256][64][1024] bf16
    unsigned* __restrict__ flags)        // [4][64] x 16 uints (64B lines)
{
  const int tid = threadIdx.x;
  const int lane = tid & 63;
  const int wv = tid >> 6;           // 0..7
  const int nh = wv & 1, kq = wv >> 1;
  const int mg = blockIdx.x & 3, ng = blockIdx.x >> 2;
  const int l15 = lane & 15, lq = lane >> 4;
  const int row = mg * 16 + l15;     // A-fragment batch row

  // barrier bookkeeping (wave 0 only uses these)
  unsigned* myflag   = flags + (size_t)(mg * 64 + ng) * 16;
  unsigned* peerflag = flags + (size_t)(mg * 64 + lane) * 16;

  __shared__ float gpart[4][16][66]; // [kq][m][gate*16+j], pad 66 vs bank conflicts

  // persistent B fragments: 2 gates x 12 ksteps = 96 VGPRs/lane
  bf16x8 bfrag[2][12];
#pragma unroll
  for (int nt = 0; nt < 2; ++nt) {
    const int ncol = (2 * nh + nt) * 1024 + ng * 16 + l15;
#pragma unroll
    for (int ks = 0; ks < 12; ++ks) {
      const int kg = kq * 384 + ks * 32 + lq * 8;   // never straddles 1024
      const float* s = (kg < 1024) ? (Whh + (size_t)ncol * 1024 + kg)
                                   : (Wih + (size_t)ncol * 512 + (kg - 1024));
      bf16x8 v;
#pragma unroll
      for (int i = 0; i < 8; ++i) v[i] = (short)f2bf(s[i]);
      bfrag[nt][ks] = v;
    }
  }

  // per-thread state (waves 0..3): one (batch m, unit j) cell each
  const int m_loc = tid >> 4, j = tid & 15;
  const int row_g = mg * 16 + m_loc;
  const int unit = ng * 16 + j;
  float c_reg = 0.f, bs0 = 0.f, bs1 = 0.f, bs2 = 0.f, bs3 = 0.f;
  if (tid < 256) {
    c_reg = c0[unit];
    bs0 = bih[unit] + bhh[unit];
    bs1 = bih[1024 + unit] + bhh[1024 + unit];
    bs2 = bih[2048 + unit] + bhh[2048 + unit];
    bs3 = bih[3072 + unit] + bhh[3072 + unit];
    hbuf[65536 + row_g * 1024 + unit] = f2bf(h0[unit]);  // h_{-1} into slot 1
  }

  // ---- barrier lambda-free helper inlined per call site ----
  // (target is monotonically increasing: 1, then t+2)
#define GROUP_BARRIER(target_expr)                                             \
  do {                                                                         \
    const unsigned _tgt = (target_expr);                                       \
    __syncthreads(); /* all waves' h/c stores drained to L2 (vmcnt0) */        \
    if (wv == 0) {                                                             \
      __hip_atomic_store(myflag, _tgt, __ATOMIC_RELEASE,                       \
                         __HIP_MEMORY_SCOPE_AGENT);                            \
      while (!__all(__hip_atomic_load(peerflag, __ATOMIC_RELAXED,              \
                                      __HIP_MEMORY_SCOPE_AGENT) >= _tgt)) {}   \
      __builtin_amdgcn_fence(__ATOMIC_ACQUIRE, "agent");                       \
    }                                                                          \
    __syncthreads();                                                           \
  } while (0)

  GROUP_BARRIER(1u);

  for (int t = 0; t < T_; ++t) {
    const unsigned short* hprev = hbuf + ((t + 1) & 1) * 65536;
    const unsigned short* bh = hprev + (size_t)row * 1024;
    const unsigned short* bx = xT + ((size_t)t * 64 + row) * 512;
    floatx4 zero = {0.f, 0.f, 0.f, 0.f};
    floatx4 acc0 = zero, acc1 = zero;
#pragma unroll
    for (int ks = 0; ks < 12; ++ks) {
      const int kg = kq * 384 + ks * 32 + lq * 8;
      const unsigned short* ap = (kg < 1024) ? (bh + kg) : (bx + (kg - 1024));
      const bf16x8 af = *(const bf16x8*)ap;
      acc0 = __builtin_amdgcn_mfma_f32_16x16x32_bf16(af, bfrag[0][ks], acc0, 0, 0, 0);
      acc1 = __builtin_amdgcn_mfma_f32_16x16x32_bf16(af, bfrag[1][ks], acc1, 0, 0, 0);
    }
    // C layout: col = lane&15, row = (lane>>4)*4 + r
#pragma unroll
    for (int r = 0; r < 4; ++r) {
      gpart[kq][lq * 4 + r][(2 * nh) * 16 + l15]     = acc0[r];
      gpart[kq][lq * 4 + r][(2 * nh + 1) * 16 + l15] = acc1[r];
    }
    __syncthreads();
    if (tid < 256) {
      float gi = bs0, gf = bs1, gg = bs2, go = bs3;
#pragma unroll
      for (int q = 0; q < 4; ++q) {
        gi += gpart[q][m_loc][j];
        gf += gpart[q][m_loc][16 + j];
        gg += gpart[q][m_loc][32 + j];
        go += gpart[q][m_loc][48 + j];
      }
      const float iv = sigm(gi), fv = sigm(gf), gv = tanhf(gg), ov = sigm(go);
      c_reg = fv * c_reg + iv * gv;
      const float hv = ov * tanhf(c_reg);
      hbuf[(t & 1) * 65536 + row_g * 1024 + unit] = f2bf(hv);
      call[((size_t)t * 64 + row_g) * 1024 + unit] = f2bf(c_reg);
    }
    GROUP_BARRIER((unsigned)(t + 2));
  }
#undef GROUP_BARRIER
}

// ---------------- output head: logits + softmax, fully parallel over t ----------------
__global__ __launch_bounds__(256, 1) void lstm_head(
    const unsigned short* __restrict__ call,
    const unsigned short* __restrict__ wout,
    const float* __restrict__ bout,
    float* __restrict__ out)
{
  const int tb = blockIdx.x;
  const int lane = threadIdx.x & 63;
  const int wv = threadIdx.x >> 6;
  const int l15 = lane & 15, lq = lane >> 4;

  __shared__ float sred[2][4][64];

  floatx4 zero = {0.f, 0.f, 0.f, 0.f};
  floatx4 acc[4][8];
#pragma unroll
  for (int mt = 0; mt < 4; ++mt)
#pragma unroll
    for (int nt = 0; nt < 8; ++nt) acc[mt][nt] = zero;

  const unsigned short* abase = call + ((size_t)tb * 64 + l15) * 1024 + lq * 8;
  const unsigned short* bbase = wout + ((size_t)(wv * 128 + l15)) * 1024 + lq * 8;

#pragma unroll 2
  for (int ks = 0; ks < 32; ++ks) {
    bf16x8 a[4];
#pragma unroll
    for (int mt = 0; mt < 4; ++mt)
      a[mt] = *(const bf16x8*)(abase + (size_t)mt * 16 * 1024 + ks * 32);
#pragma unroll
    for (int nt = 0; nt < 8; ++nt) {
      const bf16x8 b = *(const bf16x8*)(bbase + (size_t)nt * 16 * 1024 + ks * 32);
#pragma unroll
      for (int mt = 0; mt < 4; ++mt)
        acc[mt][nt] = __builtin_amdgcn_mfma_f32_16x16x32_bf16(a[mt], b, acc[mt][nt], 0, 0, 0);
    }
  }

#pragma unroll
  for (int nt = 0; nt < 8; ++nt) {
    const float bo = bout[wv * 128 + nt * 16 + l15];
#pragma unroll
    for (int mt = 0; mt < 4; ++mt)
#pragma unroll
      for (int r = 0; r < 4; ++r) acc[mt][nt][r] += bo;
  }

  float rmax[4][4];
#pragma unroll
  for (int mt = 0; mt < 4; ++mt)
#pragma unroll
    for (int r = 0; r < 4; ++r) {
      float m = acc[mt][0][r];
#pragma unroll
      for (int nt = 1; nt < 8; ++nt) m = fmaxf(m, acc[mt][nt][r]);
      m = fmaxf(m, __shfl_xor(m, 1, 64));
      m = fmaxf(m, __shfl_xor(m, 2, 64));
      m = fmaxf(m, __shfl_xor(m, 4, 64));
      m = fmaxf(m, __shfl_xor(m, 8, 64));
      rmax[mt][r] = m;
    }
  if (l15 == 0) {
#pragma unroll
    for (int mt = 0; mt < 4; ++mt)
#pragma unroll
      for (int r = 0; r < 4; ++r) sred[0][wv][mt * 16 + lq * 4 + r] = rmax[mt][r];
  }
  __syncthreads();
  float gmax[4][4], rsum[4][4];
#pragma unroll
  for (int mt = 0; mt < 4; ++mt)
#pragma unroll
    for (int r = 0; r < 4; ++r) {
      const int rw = mt * 16 + lq * 4 + r;
      gmax[mt][r] = fmaxf(fmaxf(sred[0][0][rw], sred[0][1][rw]),
                          fmaxf(sred[0][2][rw], sred[0][3][rw]));
      rsum[mt][r] = 0.f;
    }
#pragma unroll
  for (int mt = 0; mt < 4; ++mt)
#pragma unroll
    for (int nt = 0; nt < 8; ++nt)
#pragma unroll
      for (int r = 0; r < 4; ++r) {
        const float e = __expf(acc[mt][nt][r] - gmax[mt][r]);
        acc[mt][nt][r] = e;
        rsum[mt][r] += e;
      }
#pragma unroll
  for (int mt = 0; mt < 4; ++mt)
#pragma unroll
    for (int r = 0; r < 4; ++r) {
      float s = rsum[mt][r];
      s += __shfl_xor(s, 1, 64);
      s += __shfl_xor(s, 2, 64);
      s += __shfl_xor(s, 4, 64);
      s += __shfl_xor(s, 8, 64);
      rsum[mt][r] = s;
    }
  if (l15 == 0) {
#pragma unroll
    for (int mt = 0; mt < 4; ++mt)
#pragma unroll
      for (int r = 0; r < 4; ++r) sred[1][wv][mt * 16 + lq * 4 + r] = rsum[mt][r];
  }
  __syncthreads();
#pragma unroll
  for (int mt = 0; mt < 4; ++mt)
#pragma unroll
    for (int r = 0; r < 4; ++r) {
      const int rw = mt * 16 + lq * 4 + r;
      const float inv = 1.0f / (sred[1][0][rw] + sred[1][1][rw] +
                                sred[1][2][rw] + sred[1][3][rw]);
      float* orow = out + ((size_t)tb * 64 + rw) * 512 + wv * 128 + l15;
#pragma unroll
      for (int nt = 0; nt < 8; ++nt) orow[nt * 16] = acc[mt][nt][r] * inv;
    }
}

// ---------------- launch ----------------
extern "C" void kernel_launch(void* const* d_in, const int* in_sizes, int n_in,
                              void* d_out, int out_size, void* d_ws, size_t ws_size,
                              hipStream_t stream) {
  const float* x    = (const float*)d_in[0];
  const float* Wih  = (const float*)d_in[1];
  const float* Whh  = (const float*)d_in[2];
  const float* bih  = (const float*)d_in[3];
  const float* bhh  = (const float*)d_in[4];
  const float* Wout = (const float*)d_in[5];
  const float* bout = (const float*)d_in[6];
  const float* h0   = (const float*)d_in[7];
  const float* c0   = (const float*)d_in[8];
  float* out = (float*)d_out;

  char* ws = (char*)d_ws;
  unsigned* flags       = (unsigned*)(ws + 0);                  //    16 KB (4*64 lines)
  unsigned short* hbuf  = (unsigned short*)(ws + 16384);        //   256 KB
  unsigned short* woutb = (unsigned short*)(ws + 278528);       //     1 MB
  unsigned short* xT    = (unsigned short*)(ws + 1327104);      //    16 MB
  unsigned short* call  = (unsigned short*)(ws + 18104320);     //    32 MB

  hipMemsetAsync(flags, 0, 16384, stream);
  cvt_w<<<256, 256, 0, stream>>>(Wout, woutb);
  transpose_x<<<dim3(8, 16, 64), 256, 0, stream>>>(x, xT);
  lstm_rec<<<256, 512, 0, stream>>>(Whh, Wih, bih, bhh, h0, c0, xT, hbuf, call, flags);
  lstm_head<<<256, 256, 0, stream>>>(call, woutb, bout, out);
}

// Round 3
// 1479.415 us; speedup vs baseline: 8.4365x; 1.9211x over previous
//
#include <hip/hip_runtime.h>

// LSTM_27152783245909 — persistent-recurrence LSTM for MI355X (gfx950)
// R3: removed ALL cache-maintenance ops from the step loop (R2's agent
// release/acquire = buffer_wbl2 + buffer_inv per step = whole-L2 writeback/
// invalidate ≈ 10 us/step, seen as 435 KB/step FETCH). Cross-XCD data (h,
// flags) now uses targeted sc0/sc1 coherent accesses (MALL-served, no
// fences); weights/xT/call stay normally cached and remain L2-warm.
// Step: x-MFMA (overlaps wait) -> poll flags -> coop coherent h-load -> LDS
// -> h-MFMA -> reduce -> elementwise -> coherent h-store -> flag publish.

#define T_ 256

typedef __attribute__((ext_vector_type(8))) short bf16x8;
typedef __attribute__((ext_vector_type(4))) float floatx4;
typedef __attribute__((ext_vector_type(4))) int intx4;

__device__ __forceinline__ unsigned short f2bf(float f) {
  unsigned u = __builtin_bit_cast(unsigned, f);
  u += 0x7FFFu + ((u >> 16) & 1u);   // round-nearest-even
  return (unsigned short)(u >> 16);
}

__device__ __forceinline__ float sigm(float x) { return 1.0f / (1.0f + __expf(-x)); }

// ---------------- W_out fp32 -> bf16 (512x1024) ----------------
__global__ void cvt_w(const float* __restrict__ w, unsigned short* __restrict__ o) {
  const size_t g = (size_t)blockIdx.x * 256 + threadIdx.x;
  const float* s = w + g * 8;
  bf16x8 v;
#pragma unroll
  for (int i = 0; i < 8; ++i) v[i] = (short)f2bf(s[i]);
  *(bf16x8*)(o + g * 8) = v;
}

// ---------------- x[B=64, I=512, T=256] fp32 -> xT[T,B,I] bf16 ----------------
__global__ void transpose_x(const float* __restrict__ x, unsigned short* __restrict__ xT) {
  __shared__ float tile[32][33];
  const int b = blockIdx.z, i0 = blockIdx.y * 32, t0 = blockIdx.x * 32;
  const int tx = threadIdx.x & 31, ty = threadIdx.x >> 5;
#pragma unroll
  for (int p = 0; p < 4; ++p) {
    const int i = ty + p * 8;
    tile[i][tx] = x[((size_t)b * 512 + i0 + i) * 256 + t0 + tx];
  }
  __syncthreads();
#pragma unroll
  for (int p = 0; p < 4; ++p) {
    const int t = ty + p * 8;
    xT[((size_t)(t0 + t) * 64 + b) * 512 + i0 + tx] = f2bf(tile[tx][t]);
  }
}

// ---------------- persistent recurrence ----------------
// 256 blocks x 512 thr, 1 block/CU. Block (mg,ng): batch rows [16mg,16mg+16),
// hidden units [16ng,16ng+16). Wave (nh = gate pair, kq = K quarter of 1536).
// Weights in VGPRs (96/lane), c in thread registers. Coherence: h + flags via
// sc0/sc1 (MALL); no fences anywhere in the loop.
__global__ __launch_bounds__(512, 1) void lstm_rec(
    const float* __restrict__ Whh, const float* __restrict__ Wih,
    const float* __restrict__ bih, const float* __restrict__ bhh,
    const float* __restrict__ h0, const float* __restrict__ c0,
    const unsigned short* __restrict__ xT,
    unsigned short* __restrict__ hbuf,   // [2][64][1024] bf16 (coherent access only)
    unsigned short* __restrict__ call,   // [256][64][1024] bf16 (normal cached)
    unsigned* __restrict__ flags)        // [4][64] dwords, group-packed
{
  const int tid = threadIdx.x;
  const int lane = tid & 63;
  const int wv = tid >> 6;           // 0..7
  const int nh = wv & 1, kq = wv >> 1;
  const int mg = blockIdx.x & 3, ng = blockIdx.x >> 2;
  const int l15 = lane & 15, lq = lane >> 4;
  const int row = mg * 16 + l15;     // A-fragment batch row (x-part)

  unsigned* grpflags = flags + mg * 64;           // 64 dwords = 4 lines
  unsigned* myflag   = grpflags + ng;

  __shared__ unsigned short hlds[16 * 1032];      // 16 rows, stride 1032 (+8 pad)
  __shared__ float gpart[4][16][66];              // [kq][m][gate*16+j]

  // persistent B fragments: 2 gates x 12 ksteps = 96 VGPRs/lane
  bf16x8 bfrag[2][12];
#pragma unroll
  for (int nt = 0; nt < 2; ++nt) {
    const int ncol = (2 * nh + nt) * 1024 + ng * 16 + l15;
#pragma unroll
    for (int ks = 0; ks < 12; ++ks) {
      const int kg = kq * 384 + ks * 32 + lq * 8;   // never straddles 1024
      const float* s = (kg < 1024) ? (Whh + (size_t)ncol * 1024 + kg)
                                   : (Wih + (size_t)ncol * 512 + (kg - 1024));
      bf16x8 v;
#pragma unroll
      for (int i = 0; i < 8; ++i) v[i] = (short)f2bf(s[i]);
      bfrag[nt][ks] = v;
    }
  }

  // per-thread state (waves 0..3): one (batch m, unit j) cell each
  const int m_loc = tid >> 4, j = tid & 15;
  const int row_g = mg * 16 + m_loc;
  const int unit = ng * 16 + j;
  float c_reg = 0.f, bs0 = 0.f, bs1 = 0.f, bs2 = 0.f, bs3 = 0.f;
  if (tid < 256) {
    c_reg = c0[unit];
    bs0 = bih[unit] + bhh[unit];
    bs1 = bih[1024 + unit] + bhh[1024 + unit];
    bs2 = bih[2048 + unit] + bhh[2048 + unit];
    bs3 = bih[3072 + unit] + bhh[3072 + unit];
    // h_{-1} into buffer 1, coherent (write-through to MALL)
    unsigned short* hp = hbuf + 65536 + row_g * 1024 + unit;
    const unsigned hv = f2bf(h0[unit]);
    asm volatile("global_store_short %0, %1, off sc0 sc1"
                 :: "v"(hp), "v"(hv) : "memory");
    asm volatile("s_waitcnt vmcnt(0)" ::: "memory");
  }
  __syncthreads();
  if (tid == 0)
    __hip_atomic_store(myflag, 1u, __ATOMIC_RELAXED, __HIP_MEMORY_SCOPE_SYSTEM);

  for (int t = 0; t < T_; ++t) {
    const unsigned short* bx = xT + ((size_t)t * 64 + row) * 512;
    floatx4 zero = {0.f, 0.f, 0.f, 0.f};
    floatx4 acc0 = zero, acc1 = zero;

    // ---- x-part (no dependence on h_{t-1}; overlaps the flag wait) ----
#pragma unroll
    for (int ks = 0; ks < 12; ++ks) {
      const int kg = kq * 384 + ks * 32 + lq * 8;
      if (kg >= 1024) {
        const bf16x8 af = *(const bf16x8*)(bx + (kg - 1024));
        acc0 = __builtin_amdgcn_mfma_f32_16x16x32_bf16(af, bfrag[0][ks], acc0, 0, 0, 0);
        acc1 = __builtin_amdgcn_mfma_f32_16x16x32_bf16(af, bfrag[1][ks], acc1, 0, 0, 0);
      }
    }

    // ---- wait for h_{t-1} published (flag >= t+1) ----
    if (wv == 0) {
      const unsigned tgt = (unsigned)(t + 1);
      while (!__all(__hip_atomic_load(grpflags + lane, __ATOMIC_RELAXED,
                                      __HIP_MEMORY_SCOPE_SYSTEM) >= tgt)) {}
    }
    __syncthreads();

    // ---- cooperative coherent load: h rows [16mg,16mg+16) -> LDS ----
    {
      const unsigned short* hprev = hbuf + ((t + 1) & 1) * 65536;
      const unsigned short* gsrc = hprev + (size_t)(mg * 16) * 1024 + (size_t)tid * 8;
      intx4 a0, a1, a2, a3;
      asm volatile(
          "global_load_dwordx4 %0, %4, off sc0 sc1\n\t"
          "global_load_dwordx4 %1, %5, off sc0 sc1\n\t"
          "global_load_dwordx4 %2, %6, off sc0 sc1\n\t"
          "global_load_dwordx4 %3, %7, off sc0 sc1\n\t"
          "s_waitcnt vmcnt(0)"
          : "=v"(a0), "=v"(a1), "=v"(a2), "=v"(a3)
          : "v"(gsrc), "v"(gsrc + 4096), "v"(gsrc + 8192), "v"(gsrc + 12288)
          : "memory");
      intx4 av[4] = {a0, a1, a2, a3};
#pragma unroll
      for (int p = 0; p < 4; ++p) {
        const int e = tid + p * 512;            // 16B-granule index
        const int r = e >> 7, col = (e & 127) * 8;
        *(intx4*)(hlds + r * 1032 + col) = av[p];
      }
    }
    __syncthreads();

    // ---- h-part MFMAs from LDS ----
#pragma unroll
    for (int ks = 0; ks < 12; ++ks) {
      const int kg = kq * 384 + ks * 32 + lq * 8;
      if (kg < 1024) {
        const bf16x8 af = *(const bf16x8*)(hlds + l15 * 1032 + kg);
        acc0 = __builtin_amdgcn_mfma_f32_16x16x32_bf16(af, bfrag[0][ks], acc0, 0, 0, 0);
        acc1 = __builtin_amdgcn_mfma_f32_16x16x32_bf16(af, bfrag[1][ks], acc1, 0, 0, 0);
      }
    }

    // C layout: col = lane&15, row = (lane>>4)*4 + r
#pragma unroll
    for (int r = 0; r < 4; ++r) {
      gpart[kq][lq * 4 + r][(2 * nh) * 16 + l15]     = acc0[r];
      gpart[kq][lq * 4 + r][(2 * nh + 1) * 16 + l15] = acc1[r];
    }
    __syncthreads();

    if (tid < 256) {
      float gi = bs0, gf = bs1, gg = bs2, go = bs3;
#pragma unroll
      for (int q = 0; q < 4; ++q) {
        gi += gpart[q][m_loc][j];
        gf += gpart[q][m_loc][16 + j];
        gg += gpart[q][m_loc][32 + j];
        go += gpart[q][m_loc][48 + j];
      }
      const float iv = sigm(gi), fv = sigm(gf), gv = tanhf(gg), ov = sigm(go);
      c_reg = fv * c_reg + iv * gv;
      const float hv = ov * tanhf(c_reg);
      call[((size_t)t * 64 + row_g) * 1024 + unit] = f2bf(c_reg);
      unsigned short* hp = hbuf + (t & 1) * 65536 + row_g * 1024 + unit;
      const unsigned hb = f2bf(hv);
      asm volatile("global_store_short %0, %1, off sc0 sc1"
                   :: "v"(hp), "v"(hb) : "memory");
      asm volatile("s_waitcnt vmcnt(0)" ::: "memory");  // h visible at MALL
    }
    __syncthreads();
    if (tid == 0)
      __hip_atomic_store(myflag, (unsigned)(t + 2), __ATOMIC_RELAXED,
                         __HIP_MEMORY_SCOPE_SYSTEM);
  }
}

// ---------------- output head: logits + softmax, fully parallel over t ----------------
__global__ __launch_bounds__(256, 1) void lstm_head(
    const unsigned short* __restrict__ call,
    const unsigned short* __restrict__ wout,
    const float* __restrict__ bout,
    float* __restrict__ out)
{
  const int tb = blockIdx.x;
  const int lane = threadIdx.x & 63;
  const int wv = threadIdx.x >> 6;
  const int l15 = lane & 15, lq = lane >> 4;

  __shared__ float sred[2][4][64];

  floatx4 zero = {0.f, 0.f, 0.f, 0.f};
  floatx4 acc[4][8];
#pragma unroll
  for (int mt = 0; mt < 4; ++mt)
#pragma unroll
    for (int nt = 0; nt < 8; ++nt) acc[mt][nt] = zero;

  const unsigned short* abase = call + ((size_t)tb * 64 + l15) * 1024 + lq * 8;
  const unsigned short* bbase = wout + ((size_t)(wv * 128 + l15)) * 1024 + lq * 8;

#pragma unroll 2
  for (int ks = 0; ks < 32; ++ks) {
    bf16x8 a[4];
#pragma unroll
    for (int mt = 0; mt < 4; ++mt)
      a[mt] = *(const bf16x8*)(abase + (size_t)mt * 16 * 1024 + ks * 32);
#pragma unroll
    for (int nt = 0; nt < 8; ++nt) {
      const bf16x8 b = *(const bf16x8*)(bbase + (size_t)nt * 16 * 1024 + ks * 32);
#pragma unroll
      for (int mt = 0; mt < 4; ++mt)
        acc[mt][nt] = __builtin_amdgcn_mfma_f32_16x16x32_bf16(a[mt], b, acc[mt][nt], 0, 0, 0);
    }
  }

#pragma unroll
  for (int nt = 0; nt < 8; ++nt) {
    const float bo = bout[wv * 128 + nt * 16 + l15];
#pragma unroll
    for (int mt = 0; mt < 4; ++mt)
#pragma unroll
      for (int r = 0; r < 4; ++r) acc[mt][nt][r] += bo;
  }

  float rmax[4][4];
#pragma unroll
  for (int mt = 0; mt < 4; ++mt)
#pragma unroll
    for (int r = 0; r < 4; ++r) {
      float m = acc[mt][0][r];
#pragma unroll
      for (int nt = 1; nt < 8; ++nt) m = fmaxf(m, acc[mt][nt][r]);
      m = fmaxf(m, __shfl_xor(m, 1, 64));
      m = fmaxf(m, __shfl_xor(m, 2, 64));
      m = fmaxf(m, __shfl_xor(m, 4, 64));
      m = fmaxf(m, __shfl_xor(m, 8, 64));
      rmax[mt][r] = m;
    }
  if (l15 == 0) {
#pragma unroll
    for (int mt = 0; mt < 4; ++mt)
#pragma unroll
      for (int r = 0; r < 4; ++r) sred[0][wv][mt * 16 + lq * 4 + r] = rmax[mt][r];
  }
  __syncthreads();
  float gmax[4][4], rsum[4][4];
#pragma unroll
  for (int mt = 0; mt < 4; ++mt)
#pragma unroll
    for (int r = 0; r < 4; ++r) {
      const int rw = mt * 16 + lq * 4 + r;
      gmax[mt][r] = fmaxf(fmaxf(sred[0][0][rw], sred[0][1][rw]),
                          fmaxf(sred[0][2][rw], sred[0][3][rw]));
      rsum[mt][r] = 0.f;
    }
#pragma unroll
  for (int mt = 0; mt < 4; ++mt)
#pragma unroll
    for (int nt = 0; nt < 8; ++nt)
#pragma unroll
      for (int r = 0; r < 4; ++r) {
        const float e = __expf(acc[mt][nt][r] - gmax[mt][r]);
        acc[mt][nt][r] = e;
        rsum[mt][r] += e;
      }
#pragma unroll
  for (int mt = 0; mt < 4; ++mt)
#pragma unroll
    for (int r = 0; r < 4; ++r) {
      float s = rsum[mt][r];
      s += __shfl_xor(s, 1, 64);
      s += __shfl_xor(s, 2, 64);
      s += __shfl_xor(s, 4, 64);
      s += __shfl_xor(s, 8, 64);
      rsum[mt][r] = s;
    }
  if (l15 == 0) {
#pragma unroll
    for (int mt = 0; mt < 4; ++mt)
#pragma unroll
      for (int r = 0; r < 4; ++r) sred[1][wv][mt * 16 + lq * 4 + r] = rsum[mt][r];
  }
  __syncthreads();
#pragma unroll
  for (int mt = 0; mt < 4; ++mt)
#pragma unroll
    for (int r = 0; r < 4; ++r) {
      const int rw = mt * 16 + lq * 4 + r;
      const float inv = 1.0f / (sred[1][0][rw] + sred[1][1][rw] +
                                sred[1][2][rw] + sred[1][3][rw]);
      float* orow = out + ((size_t)tb * 64 + rw) * 512 + wv * 128 + l15;
#pragma unroll
      for (int nt = 0; nt < 8; ++nt) orow[nt * 16] = acc[mt][nt][r] * inv;
    }
}

// ---------------- launch ----------------
extern "C" void kernel_launch(void* const* d_in, const int* in_sizes, int n_in,
                              void* d_out, int out_size, void* d_ws, size_t ws_size,
                              hipStream_t stream) {
  const float* x    = (const float*)d_in[0];
  const float* Wih  = (const float*)d_in[1];
  const float* Whh  = (const float*)d_in[2];
  const float* bih  = (const float*)d_in[3];
  const float* bhh  = (const float*)d_in[4];
  const float* Wout = (const float*)d_in[5];
  const float* bout = (const float*)d_in[6];
  const float* h0   = (const float*)d_in[7];
  const float* c0   = (const float*)d_in[8];
  float* out = (float*)d_out;

  char* ws = (char*)d_ws;
  unsigned* flags       = (unsigned*)(ws + 0);                  //     1 KB (4*64 dwords)
  unsigned short* hbuf  = (unsigned short*)(ws + 4096);         //   256 KB
  unsigned short* woutb = (unsigned short*)(ws + 266240);       //     1 MB
  unsigned short* xT    = (unsigned short*)(ws + 1314816);      //    16 MB
  unsigned short* call  = (unsigned short*)(ws + 18092032);     //    32 MB

  hipMemsetAsync(flags, 0, 1024, stream);
  cvt_w<<<256, 256, 0, stream>>>(Wout, woutb);
  transpose_x<<<dim3(8, 16, 64), 256, 0, stream>>>(x, xT);
  lstm_rec<<<256, 512, 0, stream>>>(Whh, Wih, bih, bhh, h0, c0, xT, hbuf, call, flags);
  lstm_head<<<256, 256, 0, stream>>>(call, woutb, bout, out);
}